// Round 10
// baseline (223.451 us; speedup 1.0000x reference)
//
#include <hip/hip_runtime.h>

#define B_   4
#define N_   8192
#define S_   2048
#define C1_  128
#define C2_  256
#define CIN_ 384
#define H_   256

typedef short short8 __attribute__((ext_vector_type(8)));
typedef unsigned short ushort8 __attribute__((ext_vector_type(8)));
typedef float f32x4 __attribute__((ext_vector_type(4)));

__device__ __forceinline__ unsigned short f2bf(float x) {
  unsigned u = __float_as_uint(x);
  unsigned r = (u + 0x7fffu + ((u >> 16) & 1u)) >> 16;
  return (unsigned short)r;
}
__device__ __forceinline__ float bf2f(unsigned short h) {
  return __uint_as_float(((unsigned)h) << 16);
}
__device__ __forceinline__ void async16(const void* g, void* l) {
  __builtin_amdgcn_global_load_lds(
      (const __attribute__((address_space(1))) void*)g,
      (__attribute__((address_space(3))) void*)l, 16, 0, 0);
}

// ===========================================================================
// PREP kernel: convW + p2->p2t + p1->Xt (block-uniform branches). 2176 blocks.
// ===========================================================================
__device__ __forceinline__ void transpose_tile(
    const float* __restrict__ src, unsigned short* __restrict__ dst,
    float* tile, int x, int y, int z, int C, int Nsrc, int dstStride, int tid) {
  const int n0 = x * 64, c0 = y * 64;
  const float* sp = src + ((size_t)z * C + c0) * Nsrc;
  unsigned short* dp = dst + (size_t)z * Nsrc * dstStride;
  const int c_l = tid >> 2, nch = (tid & 3) * 16;
  const float* s = sp + (size_t)c_l * Nsrc + n0 + nch;
#pragma unroll
  for (int i = 0; i < 4; ++i)
    *(float4*)&tile[c_l * 65 + nch + i * 4] = *(const float4*)(s + i * 4);
  __syncthreads();
  const int n_l = tid >> 2, cch = (tid & 3) * 16;
  unsigned short pk[16];
#pragma unroll
  for (int i = 0; i < 16; ++i) pk[i] = f2bf(tile[(cch + i) * 65 + n_l]);
  unsigned short* d = dp + (size_t)(n0 + n_l) * dstStride + c0 + cch;
  *(uint4*)d = *(uint4*)pk;
  *(uint4*)(d + 8) = *(uint4*)(pk + 8);
}

__global__ __launch_bounds__(256) void prep_kernel(
    const float* __restrict__ W1, const float* __restrict__ W2,
    unsigned short* __restrict__ W1b, unsigned short* __restrict__ W2b,
    const float* __restrict__ p1, const float* __restrict__ p2,
    unsigned short* __restrict__ Xt, unsigned short* __restrict__ p2t) {
  __shared__ float tile[64 * 65];
  const int blk = blockIdx.x, tid = threadIdx.x;

  if (blk < 640) {                       // ---- convW (163840 elements)
    int id = blk * 256 + tid;
    if (id < 98304) W1b[id] = f2bf(W1[id]);
    else            W2b[id - 98304] = f2bf(W2[id - 98304]);
    return;
  }
  if (blk < 1152) {                      // ---- p2 [4][256][2048] -> p2t
    int t = blk - 640;
    transpose_tile(p2, p2t, tile, t & 31, (t >> 5) & 3, t >> 7,
                   C2_, S_, C2_, tid);
    return;
  }
  {                                      // ---- p1 [4][128][8192] -> Xt[:,0:128)
    int t = blk - 1152;                  // 1024 blocks
    transpose_tile(p1, Xt, tile, t & 127, (t >> 7) & 1, t >> 8,
                   C1_, N_, CIN_, tid);
  }
}

// ===========================================================================
// KNN + INTERP fused: 512 blocks x 256 threads, 64 queries/block.
// Phase 1: exact-fp32 3-NN, wave-uniform rejection branch + med3 maintenance.
// Phase 2: same block gathers 3 p2t rows per query, blends, writes Xt.
// ===========================================================================
__global__ __launch_bounds__(256) void knn_interp_kernel(
    const float* __restrict__ xyz1, const float* __restrict__ xyz2,
    const unsigned short* __restrict__ p2t, unsigned short* __restrict__ Xt) {
  __shared__ float4 t4[S_];        // 32 KB
  __shared__ float kd[64][13];
  __shared__ int   ki[64][13];
  __shared__ int   sidx[64][3];
  __shared__ float swgt[64][3];
  const int blk = blockIdx.x;
  const int b  = blk >> 7;
  const int n0 = (blk & 127) << 6;
  const int tid = threadIdx.x;

  for (int i = tid; i < S_; i += 256) {
    float x = xyz2[(b * S_ + i) * 3 + 0];
    float y = xyz2[(b * S_ + i) * 3 + 1];
    float z = xyz2[(b * S_ + i) * 3 + 2];
    t4[i] = make_float4(-2.f * x, -2.f * y, -2.f * z,
                        fmaf(x, x, fmaf(y, y, z * z)));
  }
  __syncthreads();

  {
    const int w = tid >> 6;      // wave 0..3 -> candidate slice of 512
    const int ln = tid & 63;
    const int n = n0 + ln;
    const float px = xyz1[(b * N_ + n) * 3 + 0];
    const float py = xyz1[(b * N_ + n) * 3 + 1];
    const float pz = xyz1[(b * N_ + n) * 3 + 2];
    const float h = fmaf(px, px, fmaf(py, py, pz * pz));

    float d0 = 1e30f, d1 = 1e30f, d2 = 1e30f;
    int j0 = 0, j1 = 0, j2 = 0;
    const int jg0 = w * 512;
    const float4* tp = t4 + jg0;
#pragma unroll 4
    for (int j = 0; j < 512; ++j) {
      float4 tt = tp[j];   // wave-uniform address -> LDS broadcast
      float d = fmaf(px, tt.x, fmaf(py, tt.y, fmaf(pz, tt.z, tt.w))) + h;
      d = fmaxf(d, 0.f);
      if (__any(d < d2)) {           // wave-uniform skip of the network
        const int jj = jg0 + j;
        bool c0 = d < d0, c1 = d < d1, c2 = d < d2;
        int nj2 = c1 ? j1 : (c2 ? jj : j2);
        int nj1 = c0 ? j0 : (c1 ? jj : j1);
        j0 = c0 ? jj : j0;
        float nd2 = fminf(fmaxf(d, d1), d2);   // med3(d, d1, d2)
        float nd1 = fminf(fmaxf(d, d0), d1);   // med3(d, d0, d1)
        d0 = fminf(d, d0);
        d1 = nd1; d2 = nd2;
        j1 = nj1; j2 = nj2;
      }
    }
    kd[ln][w * 3 + 0] = d0; ki[ln][w * 3 + 0] = j0;
    kd[ln][w * 3 + 1] = d1; ki[ln][w * 3 + 1] = j1;
    kd[ln][w * 3 + 2] = d2; ki[ln][w * 3 + 2] = j2;
  }
  __syncthreads();

  if (tid < 64) {
    float m0 = kd[tid][0], m1 = kd[tid][1], m2 = kd[tid][2];
    int   i0 = ki[tid][0], i1 = ki[tid][1], i2 = ki[tid][2];
#pragma unroll
    for (int s = 3; s < 12; ++s) {
      float d = kd[tid][s];
      int  jj = ki[tid][s];
      bool c0 = d < m0, c1 = d < m1, c2 = d < m2;
      int nj2 = c1 ? i1 : (c2 ? jj : i2);
      int nj1 = c0 ? i0 : (c1 ? jj : i1);
      i0 = c0 ? jj : i0;
      float nd2 = fminf(fmaxf(d, m1), m2);
      float nd1 = fminf(fmaxf(d, m0), m1);
      m0 = fminf(d, m0);
      m1 = nd1; m2 = nd2;
      i1 = nj1; i2 = nj2;
    }
    float r0 = 1.f / (m0 + 1e-8f);
    float r1 = 1.f / (m1 + 1e-8f);
    float r2 = 1.f / (m2 + 1e-8f);
    float rs = 1.f / (r0 + r1 + r2);
    sidx[tid][0] = i0; sidx[tid][1] = i1; sidx[tid][2] = i2;
    swgt[tid][0] = r0 * rs; swgt[tid][1] = r1 * rs; swgt[tid][2] = r2 * rs;
  }
  __syncthreads();

  // interp: wave w handles queries w*16..w*16+15; lane = 4 channels
  {
    const int w = tid >> 6, lane = tid & 63;
#pragma unroll 2
    for (int i = 0; i < 16; ++i) {
      const int q = w * 16 + i;
      const int gn = b * N_ + n0 + q;
      int i0 = sidx[q][0], i1 = sidx[q][1], i2 = sidx[q][2];
      float w0 = swgt[q][0], w1 = swgt[q][1], w2 = swgt[q][2];
      uint2 x = *(const uint2*)(p2t + (((size_t)(b * S_ + i0)) << 8) + lane * 4);
      uint2 y = *(const uint2*)(p2t + (((size_t)(b * S_ + i1)) << 8) + lane * 4);
      uint2 z = *(const uint2*)(p2t + (((size_t)(b * S_ + i2)) << 8) + lane * 4);
      const unsigned short* xp = (const unsigned short*)&x;
      const unsigned short* yp = (const unsigned short*)&y;
      const unsigned short* zp = (const unsigned short*)&z;
      unsigned short pk[4];
#pragma unroll
      for (int k = 0; k < 4; ++k) {
        float v = w0 * bf2f(xp[k]) + w1 * bf2f(yp[k]) + w2 * bf2f(zp[k]);
        pk[k] = f2bf(v);
      }
      *(uint2*)(Xt + (size_t)gn * CIN_ + C1_ + lane * 4) = *(uint2*)pk;
    }
  }
}

// ===========================================================================
// bf16 MFMA GEMM (proven): 128x128 tile, BK=32, 4x4 16x16x32/wave.
// ===========================================================================
template <int K, bool FUSE>
__global__ __launch_bounds__(256, 2) void gemm_mfma_kernel(
    const unsigned short* __restrict__ Wb,
    const unsigned short* __restrict__ Bmat,
    const float* __restrict__ bias,
    const float* __restrict__ bnscale, const float* __restrict__ bnshift,
    float* __restrict__ OutF, unsigned short* __restrict__ OutB,
    float* __restrict__ Psum, float* __restrict__ Psq) {
  __shared__ __align__(16) short Als[128 * 32];
  __shared__ __align__(16) short Bls[128 * 32];
  const int tid = threadIdx.x;
  const int lane = tid & 63;
  const int col = lane & 15, quad = lane >> 4;
  const int wid = tid >> 6;
  const int wr = wid >> 1, wc = wid & 1;
  const int nBase = blockIdx.x * 128;
  const int oBase = blockIdx.y * 128;
  const int b = blockIdx.z;

  f32x4 acc[4][4];
#pragma unroll
  for (int i = 0; i < 4; ++i)
#pragma unroll
    for (int j = 0; j < 4; ++j) acc[i][j] = (f32x4){0.f, 0.f, 0.f, 0.f};

  const int f0 = tid * 16;
  const int m0 = f0 >> 6;
  const int kb0 = f0 & 63;
  const char* Abase = (const char*)Wb;
  const char* Bbase = (const char*)Bmat;
  char* AldsW = (char*)Als + (tid & ~63) * 16;
  char* BldsW = (char*)Bls + (tid & ~63) * 16;

  for (int k0 = 0; k0 < K; k0 += 32) {
    __syncthreads();
    async16(Abase + ((size_t)(oBase + m0) * K + k0) * 2 + kb0, AldsW);
    async16(Abase + ((size_t)(oBase + m0 + 64) * K + k0) * 2 + kb0, AldsW + 4096);
    if (!FUSE) {
      async16(Bbase + ((size_t)(b * N_ + nBase + m0) * K + k0) * 2 + kb0, BldsW);
      async16(Bbase + ((size_t)(b * N_ + nBase + m0 + 64) * K + k0) * 2 + kb0,
              BldsW + 4096);
    } else {
#pragma unroll
      for (int r = 0; r < 2; ++r) {
        const int f = f0 + r * 4096;
        const int n = f >> 6;
        const int kb = f & 63;
        const int ke = k0 + (kb >> 1);
        ushort8 h = *(const ushort8*)(Bbase +
            ((size_t)(b * N_ + nBase + n) * K + k0) * 2 + kb);
        float4 s0 = *(const float4*)(bnscale + ke);
        float4 s1 = *(const float4*)(bnscale + ke + 4);
        float4 t0 = *(const float4*)(bnshift + ke);
        float4 t1 = *(const float4*)(bnshift + ke + 4);
        float sc[8] = {s0.x, s0.y, s0.z, s0.w, s1.x, s1.y, s1.z, s1.w};
        float sh[8] = {t0.x, t0.y, t0.z, t0.w, t1.x, t1.y, t1.z, t1.w};
        unsigned short pk[8];
#pragma unroll
        for (int e = 0; e < 8; ++e)
          pk[e] = f2bf(fmaxf(fmaf(bf2f(h[e]), sc[e], sh[e]), 0.f));
        *(uint4*)((char*)Bls + f) = *(uint4*)pk;
      }
    }
    __syncthreads();
    short8 af[4], bfr[4];
#pragma unroll
    for (int i = 0; i < 4; ++i)
      af[i] = *(const short8*)(Als + (wr * 64 + i * 16 + col) * 32 + quad * 8);
#pragma unroll
    for (int j = 0; j < 4; ++j)
      bfr[j] = *(const short8*)(Bls + (wc * 64 + j * 16 + col) * 32 + quad * 8);
#pragma unroll
    for (int i = 0; i < 4; ++i)
#pragma unroll
      for (int j = 0; j < 4; ++j)
        acc[i][j] = __builtin_amdgcn_mfma_f32_16x16x32_bf16(af[i], bfr[j],
                                                            acc[i][j], 0, 0, 0);
  }

  float s_acc[4][4], q_acc[4][4];
#pragma unroll
  for (int i = 0; i < 4; ++i) {
    const int oloc = wr * 64 + i * 16 + quad * 4;
    float4 bb = *(const float4*)(bias + oBase + oloc);
    float s[4] = {0.f, 0.f, 0.f, 0.f}, q[4] = {0.f, 0.f, 0.f, 0.f};
#pragma unroll
    for (int j = 0; j < 4; ++j) {
      const int n = nBase + wc * 64 + j * 16 + col;
      float v0 = acc[i][j][0] + bb.x;
      float v1 = acc[i][j][1] + bb.y;
      float v2 = acc[i][j][2] + bb.z;
      float v3 = acc[i][j][3] + bb.w;
      if (!FUSE) {
        unsigned short pk[4] = {f2bf(v0), f2bf(v1), f2bf(v2), f2bf(v3)};
        *(uint2*)(OutB + (size_t)(b * N_ + n) * H_ + oBase + oloc) = *(uint2*)pk;
      } else {
        float* op = OutF + ((size_t)b * H_ + oBase + oloc) * N_ + n;
        op[0] = v0; op[N_] = v1; op[2 * N_] = v2; op[3 * N_] = v3;
      }
      s[0] += v0; q[0] = fmaf(v0, v0, q[0]);
      s[1] += v1; q[1] = fmaf(v1, v1, q[1]);
      s[2] += v2; q[2] = fmaf(v2, v2, q[2]);
      s[3] += v3; q[3] = fmaf(v3, v3, q[3]);
    }
#pragma unroll
    for (int reg = 0; reg < 4; ++reg) {
      float ss = s[reg], qq = q[reg];
#pragma unroll
      for (int m = 1; m < 16; m <<= 1) {
        ss += __shfl_xor(ss, m);
        qq += __shfl_xor(qq, m);
      }
      s_acc[i][reg] = ss;
      q_acc[i][reg] = qq;
    }
  }
  __syncthreads();
  float* red = (float*)Als;
#pragma unroll
  for (int i = 0; i < 4; ++i)
#pragma unroll
    for (int reg = 0; reg < 4; ++reg)
      if (col == 0) {
        int ch = wr * 64 + i * 16 + quad * 4 + reg;
        red[wc * 256 + ch] = s_acc[i][reg];
        red[wc * 256 + 128 + ch] = q_acc[i][reg];
      }
  __syncthreads();
  {
    const int wcb = tid >> 7, ch = tid & 127;
    const int part = (blockIdx.z * 64 + blockIdx.x) * 2 + wcb;
    Psum[part * 256 + oBase + ch] = red[wcb * 256 + ch];
    Psq[part * 256 + oBase + ch]  = red[wcb * 256 + 128 + ch];
  }
}

// ===========================================================================
__global__ __launch_bounds__(1024) void finalize_bn_kernel(
    const float* __restrict__ Psum, const float* __restrict__ Psq,
    const float* __restrict__ gamma, const float* __restrict__ beta,
    float* __restrict__ scale, float* __restrict__ shift) {
  __shared__ float ls[4][2][256];
  const int tid = threadIdx.x;
  const int g = tid >> 8, ch = tid & 255;
  float s = 0.f, q = 0.f;
#pragma unroll 4
  for (int p = g * 128; p < (g + 1) * 128; ++p) {
    s += Psum[p * 256 + ch];
    q += Psq[p * 256 + ch];
  }
  ls[g][0][ch] = s;
  ls[g][1][ch] = q;
  __syncthreads();
  if (tid < 256) {
    float ss = ls[0][0][ch] + ls[1][0][ch] + ls[2][0][ch] + ls[3][0][ch];
    float qq = ls[0][1][ch] + ls[1][1][ch] + ls[2][1][ch] + ls[3][1][ch];
    const float inv_n = 1.f / 32768.f;
    float mean = ss * inv_n;
    float var = qq * inv_n - mean * mean;
    float sc = gamma[ch] * rsqrtf(var + 1e-5f);
    scale[ch] = sc;
    shift[ch] = fmaf(-mean, sc, beta[ch]);
  }
}

__global__ __launch_bounds__(256) void bn_apply_kernel(float* __restrict__ io,
                                                       const float* __restrict__ scale,
                                                       const float* __restrict__ shift) {
  int id = blockIdx.x * 256 + threadIdx.x;
  int row = id >> 11;
  int o = row & 255;
  float sc = scale[o], sh = shift[o];
  float4 v = ((float4*)io)[id];
  v.x = fmaxf(fmaf(v.x, sc, sh), 0.f);
  v.y = fmaxf(fmaf(v.y, sc, sh), 0.f);
  v.z = fmaxf(fmaf(v.z, sc, sh), 0.f);
  v.w = fmaxf(fmaf(v.w, sc, sh), 0.f);
  ((float4*)io)[id] = v;
}

// ===========================================================================
extern "C" void kernel_launch(void* const* d_in, const int* in_sizes, int n_in,
                              void* d_out, int out_size, void* d_ws, size_t ws_size,
                              hipStream_t stream) {
  const float* xyz1 = (const float*)d_in[0];
  const float* xyz2 = (const float*)d_in[1];
  const float* p1   = (const float*)d_in[2];
  const float* p2   = (const float*)d_in[3];
  const float* W1   = (const float*)d_in[4];
  const float* b1   = (const float*)d_in[5];
  const float* g1   = (const float*)d_in[6];
  const float* be1  = (const float*)d_in[7];
  const float* W2   = (const float*)d_in[8];
  const float* b2   = (const float*)d_in[9];
  const float* g2   = (const float*)d_in[10];
  const float* be2  = (const float*)d_in[11];
  float* out = (float*)d_out;

  unsigned short* ws = (unsigned short*)d_ws;
  unsigned short* Xt  = ws;                    // [B][N][384]  12,582,912 bf16
  unsigned short* Y1t = Xt + 12582912;         // [B][N][256]   8,388,608 bf16
  unsigned short* p2t = Y1t + 8388608;         // [B][S][256]   2,097,152 bf16
  unsigned short* W1b = p2t + 2097152;         //      98,304 bf16
  unsigned short* W2b = W1b + 98304;           //      65,536 bf16
  float* Psum1 = (float*)(W2b + 65536);        //     131,072 f
  float* Psq1  = Psum1 + 131072;
  float* Psum2 = Psq1 + 131072;
  float* Psq2  = Psum2 + 131072;
  float* scale1 = Psq2 + 131072;
  float* shift1 = scale1 + 256;
  float* scale2 = shift1 + 256;
  float* shift2 = scale2 + 256;

  prep_kernel<<<2176, 256, 0, stream>>>(W1, W2, W1b, W2b, p1, p2, Xt, p2t);
  knn_interp_kernel<<<512, 256, 0, stream>>>(xyz1, xyz2, p2t, Xt);

  dim3 gg(64, 2, 4);
  gemm_mfma_kernel<CIN_, false><<<gg, 256, 0, stream>>>(
      W1b, Xt, b1, nullptr, nullptr, nullptr, Y1t, Psum1, Psq1);
  finalize_bn_kernel<<<1, 1024, 0, stream>>>(Psum1, Psq1, g1, be1, scale1, shift1);
  gemm_mfma_kernel<H_, true><<<gg, 256, 0, stream>>>(
      W2b, Y1t, b2, scale1, shift1, out, nullptr, Psum2, Psq2);
  finalize_bn_kernel<<<1, 1024, 0, stream>>>(Psum2, Psq2, g2, be2, scale2, shift2);
  bn_apply_kernel<<<8192, 256, 0, stream>>>(out, scale2, shift2);
}

// Round 11
// 206.031 us; speedup vs baseline: 1.0846x; 1.0846x over previous
//
#include <hip/hip_runtime.h>

#define B_   4
#define N_   8192
#define S_   2048
#define C1_  128
#define C2_  256
#define CIN_ 384
#define H_   256

typedef short short8 __attribute__((ext_vector_type(8)));
typedef unsigned short ushort8 __attribute__((ext_vector_type(8)));
typedef float f32x4 __attribute__((ext_vector_type(4)));

__device__ __forceinline__ unsigned short f2bf(float x) {
  unsigned u = __float_as_uint(x);
  unsigned r = (u + 0x7fffu + ((u >> 16) & 1u)) >> 16;
  return (unsigned short)r;
}
__device__ __forceinline__ float bf2f(unsigned short h) {
  return __uint_as_float(((unsigned)h) << 16);
}
__device__ __forceinline__ void async16(const void* g, void* l) {
  __builtin_amdgcn_global_load_lds(
      (const __attribute__((address_space(1))) void*)g,
      (__attribute__((address_space(3))) void*)l, 16, 0, 0);
}

// ===========================================================================
// PREP kernel: convW + p2->p2t + p1->Xt (block-uniform branches). 2176 blocks.
// ===========================================================================
__device__ __forceinline__ void transpose_tile(
    const float* __restrict__ src, unsigned short* __restrict__ dst,
    float* tile, int x, int y, int z, int C, int Nsrc, int dstStride, int tid) {
  const int n0 = x * 64, c0 = y * 64;
  const float* sp = src + ((size_t)z * C + c0) * Nsrc;
  unsigned short* dp = dst + (size_t)z * Nsrc * dstStride;
  const int c_l = tid >> 2, nch = (tid & 3) * 16;
  const float* s = sp + (size_t)c_l * Nsrc + n0 + nch;
#pragma unroll
  for (int i = 0; i < 4; ++i)
    *(float4*)&tile[c_l * 65 + nch + i * 4] = *(const float4*)(s + i * 4);
  __syncthreads();
  const int n_l = tid >> 2, cch = (tid & 3) * 16;
  unsigned short pk[16];
#pragma unroll
  for (int i = 0; i < 16; ++i) pk[i] = f2bf(tile[(cch + i) * 65 + n_l]);
  unsigned short* d = dp + (size_t)(n0 + n_l) * dstStride + c0 + cch;
  *(uint4*)d = *(uint4*)pk;
  *(uint4*)(d + 8) = *(uint4*)(pk + 8);
}

__global__ __launch_bounds__(256) void prep_kernel(
    const float* __restrict__ W1, const float* __restrict__ W2,
    unsigned short* __restrict__ W1b, unsigned short* __restrict__ W2b,
    const float* __restrict__ p1, const float* __restrict__ p2,
    unsigned short* __restrict__ Xt, unsigned short* __restrict__ p2t) {
  __shared__ float tile[64 * 65];
  const int blk = blockIdx.x, tid = threadIdx.x;

  if (blk < 640) {                       // ---- convW (163840 elements)
    int id = blk * 256 + tid;
    if (id < 98304) W1b[id] = f2bf(W1[id]);
    else            W2b[id - 98304] = f2bf(W2[id - 98304]);
    return;
  }
  if (blk < 1152) {                      // ---- p2 [4][256][2048] -> p2t
    int t = blk - 640;
    transpose_tile(p2, p2t, tile, t & 31, (t >> 5) & 3, t >> 7,
                   C2_, S_, C2_, tid);
    return;
  }
  {                                      // ---- p1 [4][128][8192] -> Xt[:,0:128)
    int t = blk - 1152;                  // 1024 blocks
    transpose_tile(p1, Xt, tile, t & 127, (t >> 7) & 1, t >> 8,
                   C1_, N_, CIN_, tid);
  }
}

// ===========================================================================
// KNN + INTERP fused v2: 512 blocks x 512 threads (8 waves), 64 queries/block.
// Phase 1: 8 waves x 256 candidates each (16 waves/CU — 2x TLP vs r9),
//          exact-fp32 branchless cndmask insertion (proven round-9 network).
// Phase 2: merge 24 partials/query; phase 3: 8-wave interp gather -> Xt.
// ===========================================================================
__global__ __launch_bounds__(512) void knn_interp_kernel(
    const float* __restrict__ xyz1, const float* __restrict__ xyz2,
    const unsigned short* __restrict__ p2t, unsigned short* __restrict__ Xt) {
  __shared__ float4 t4[S_];        // 32 KB
  __shared__ float kd[64][25];     // stride 25: conflict-free
  __shared__ int   ki[64][25];
  __shared__ int   sidx[64][3];
  __shared__ float swgt[64][3];
  const int blk = blockIdx.x;
  const int b  = blk >> 7;
  const int n0 = (blk & 127) << 6;
  const int tid = threadIdx.x;

  for (int i = tid; i < S_; i += 512) {
    float x = xyz2[(b * S_ + i) * 3 + 0];
    float y = xyz2[(b * S_ + i) * 3 + 1];
    float z = xyz2[(b * S_ + i) * 3 + 2];
    t4[i] = make_float4(-2.f * x, -2.f * y, -2.f * z,
                        fmaf(x, x, fmaf(y, y, z * z)));
  }
  __syncthreads();

  {
    const int w = tid >> 6;      // wave 0..7 -> candidate slice of 256
    const int ln = tid & 63;
    const int n = n0 + ln;
    const float px = xyz1[(b * N_ + n) * 3 + 0];
    const float py = xyz1[(b * N_ + n) * 3 + 1];
    const float pz = xyz1[(b * N_ + n) * 3 + 2];
    const float h = fmaf(px, px, fmaf(py, py, pz * pz));

    float d0 = 1e30f, d1 = 1e30f, d2 = 1e30f;
    int j0 = 0, j1 = 0, j2 = 0;
    const int jg0 = w * 256;
    const float4* tp = t4 + jg0;
#pragma unroll 4
    for (int j = 0; j < 256; ++j) {
      float4 tt = tp[j];   // wave-uniform address -> LDS broadcast
      float d = fmaf(px, tt.x, fmaf(py, tt.y, fmaf(pz, tt.z, tt.w))) + h;
      d = fmaxf(d, 0.f);
      const int jj = jg0 + j;
      bool c0 = d < d0, c1 = d < d1, c2 = d < d2;
      float nd2 = c1 ? d1 : (c2 ? d : d2);
      int   nj2 = c1 ? j1 : (c2 ? jj : j2);
      float nd1 = c0 ? d0 : (c1 ? d : d1);
      int   nj1 = c0 ? j0 : (c1 ? jj : j1);
      d0 = c0 ? d : d0;
      j0 = c0 ? jj : j0;
      d1 = nd1; j1 = nj1;
      d2 = nd2; j2 = nj2;
    }
    kd[ln][w * 3 + 0] = d0; ki[ln][w * 3 + 0] = j0;
    kd[ln][w * 3 + 1] = d1; ki[ln][w * 3 + 1] = j1;
    kd[ln][w * 3 + 2] = d2; ki[ln][w * 3 + 2] = j2;
  }
  __syncthreads();

  if (tid < 64) {
    float m0 = kd[tid][0], m1 = kd[tid][1], m2 = kd[tid][2];
    int   i0 = ki[tid][0], i1 = ki[tid][1], i2 = ki[tid][2];
#pragma unroll
    for (int s = 3; s < 24; ++s) {
      float d = kd[tid][s];
      int  jj = ki[tid][s];
      bool c0 = d < m0, c1 = d < m1, c2 = d < m2;
      float nd2 = c1 ? m1 : (c2 ? d : m2);
      int   nj2 = c1 ? i1 : (c2 ? jj : i2);
      float nd1 = c0 ? m0 : (c1 ? d : m1);
      int   nj1 = c0 ? i0 : (c1 ? jj : i1);
      m0 = c0 ? d : m0;
      i0 = c0 ? jj : i0;
      m1 = nd1; i1 = nj1;
      m2 = nd2; i2 = nj2;
    }
    float r0 = 1.f / (m0 + 1e-8f);
    float r1 = 1.f / (m1 + 1e-8f);
    float r2 = 1.f / (m2 + 1e-8f);
    float rs = 1.f / (r0 + r1 + r2);
    sidx[tid][0] = i0; sidx[tid][1] = i1; sidx[tid][2] = i2;
    swgt[tid][0] = r0 * rs; swgt[tid][1] = r1 * rs; swgt[tid][2] = r2 * rs;
  }
  __syncthreads();

  // interp: wave w handles queries w*8..w*8+7; lane = 4 channels
  {
    const int w = tid >> 6, lane = tid & 63;
#pragma unroll 2
    for (int i = 0; i < 8; ++i) {
      const int q = w * 8 + i;
      const int gn = b * N_ + n0 + q;
      int i0 = sidx[q][0], i1 = sidx[q][1], i2 = sidx[q][2];
      float w0 = swgt[q][0], w1 = swgt[q][1], w2 = swgt[q][2];
      uint2 x = *(const uint2*)(p2t + (((size_t)(b * S_ + i0)) << 8) + lane * 4);
      uint2 y = *(const uint2*)(p2t + (((size_t)(b * S_ + i1)) << 8) + lane * 4);
      uint2 z = *(const uint2*)(p2t + (((size_t)(b * S_ + i2)) << 8) + lane * 4);
      const unsigned short* xp = (const unsigned short*)&x;
      const unsigned short* yp = (const unsigned short*)&y;
      const unsigned short* zp = (const unsigned short*)&z;
      unsigned short pk[4];
#pragma unroll
      for (int k = 0; k < 4; ++k) {
        float v = w0 * bf2f(xp[k]) + w1 * bf2f(yp[k]) + w2 * bf2f(zp[k]);
        pk[k] = f2bf(v);
      }
      *(uint2*)(Xt + (size_t)gn * CIN_ + C1_ + lane * 4) = *(uint2*)pk;
    }
  }
}

// ===========================================================================
// bf16 MFMA GEMM (proven): 128x128 tile, BK=32, 4x4 16x16x32/wave.
// ===========================================================================
template <int K, bool FUSE>
__global__ __launch_bounds__(256, 2) void gemm_mfma_kernel(
    const unsigned short* __restrict__ Wb,
    const unsigned short* __restrict__ Bmat,
    const float* __restrict__ bias,
    const float* __restrict__ bnscale, const float* __restrict__ bnshift,
    float* __restrict__ OutF, unsigned short* __restrict__ OutB,
    float* __restrict__ Psum, float* __restrict__ Psq) {
  __shared__ __align__(16) short Als[128 * 32];
  __shared__ __align__(16) short Bls[128 * 32];
  const int tid = threadIdx.x;
  const int lane = tid & 63;
  const int col = lane & 15, quad = lane >> 4;
  const int wid = tid >> 6;
  const int wr = wid >> 1, wc = wid & 1;
  const int nBase = blockIdx.x * 128;
  const int oBase = blockIdx.y * 128;
  const int b = blockIdx.z;

  f32x4 acc[4][4];
#pragma unroll
  for (int i = 0; i < 4; ++i)
#pragma unroll
    for (int j = 0; j < 4; ++j) acc[i][j] = (f32x4){0.f, 0.f, 0.f, 0.f};

  const int f0 = tid * 16;
  const int m0 = f0 >> 6;
  const int kb0 = f0 & 63;
  const char* Abase = (const char*)Wb;
  const char* Bbase = (const char*)Bmat;
  char* AldsW = (char*)Als + (tid & ~63) * 16;
  char* BldsW = (char*)Bls + (tid & ~63) * 16;

  for (int k0 = 0; k0 < K; k0 += 32) {
    __syncthreads();
    async16(Abase + ((size_t)(oBase + m0) * K + k0) * 2 + kb0, AldsW);
    async16(Abase + ((size_t)(oBase + m0 + 64) * K + k0) * 2 + kb0, AldsW + 4096);
    if (!FUSE) {
      async16(Bbase + ((size_t)(b * N_ + nBase + m0) * K + k0) * 2 + kb0, BldsW);
      async16(Bbase + ((size_t)(b * N_ + nBase + m0 + 64) * K + k0) * 2 + kb0,
              BldsW + 4096);
    } else {
#pragma unroll
      for (int r = 0; r < 2; ++r) {
        const int f = f0 + r * 4096;
        const int n = f >> 6;
        const int kb = f & 63;
        const int ke = k0 + (kb >> 1);
        ushort8 h = *(const ushort8*)(Bbase +
            ((size_t)(b * N_ + nBase + n) * K + k0) * 2 + kb);
        float4 s0 = *(const float4*)(bnscale + ke);
        float4 s1 = *(const float4*)(bnscale + ke + 4);
        float4 t0 = *(const float4*)(bnshift + ke);
        float4 t1 = *(const float4*)(bnshift + ke + 4);
        float sc[8] = {s0.x, s0.y, s0.z, s0.w, s1.x, s1.y, s1.z, s1.w};
        float sh[8] = {t0.x, t0.y, t0.z, t0.w, t1.x, t1.y, t1.z, t1.w};
        unsigned short pk[8];
#pragma unroll
        for (int e = 0; e < 8; ++e)
          pk[e] = f2bf(fmaxf(fmaf(bf2f(h[e]), sc[e], sh[e]), 0.f));
        *(uint4*)((char*)Bls + f) = *(uint4*)pk;
      }
    }
    __syncthreads();
    short8 af[4], bfr[4];
#pragma unroll
    for (int i = 0; i < 4; ++i)
      af[i] = *(const short8*)(Als + (wr * 64 + i * 16 + col) * 32 + quad * 8);
#pragma unroll
    for (int j = 0; j < 4; ++j)
      bfr[j] = *(const short8*)(Bls + (wc * 64 + j * 16 + col) * 32 + quad * 8);
#pragma unroll
    for (int i = 0; i < 4; ++i)
#pragma unroll
      for (int j = 0; j < 4; ++j)
        acc[i][j] = __builtin_amdgcn_mfma_f32_16x16x32_bf16(af[i], bfr[j],
                                                            acc[i][j], 0, 0, 0);
  }

  float s_acc[4][4], q_acc[4][4];
#pragma unroll
  for (int i = 0; i < 4; ++i) {
    const int oloc = wr * 64 + i * 16 + quad * 4;
    float4 bb = *(const float4*)(bias + oBase + oloc);
    float s[4] = {0.f, 0.f, 0.f, 0.f}, q[4] = {0.f, 0.f, 0.f, 0.f};
#pragma unroll
    for (int j = 0; j < 4; ++j) {
      const int n = nBase + wc * 64 + j * 16 + col;
      float v0 = acc[i][j][0] + bb.x;
      float v1 = acc[i][j][1] + bb.y;
      float v2 = acc[i][j][2] + bb.z;
      float v3 = acc[i][j][3] + bb.w;
      if (!FUSE) {
        unsigned short pk[4] = {f2bf(v0), f2bf(v1), f2bf(v2), f2bf(v3)};
        *(uint2*)(OutB + (size_t)(b * N_ + n) * H_ + oBase + oloc) = *(uint2*)pk;
      } else {
        float* op = OutF + ((size_t)b * H_ + oBase + oloc) * N_ + n;
        op[0] = v0; op[N_] = v1; op[2 * N_] = v2; op[3 * N_] = v3;
      }
      s[0] += v0; q[0] = fmaf(v0, v0, q[0]);
      s[1] += v1; q[1] = fmaf(v1, v1, q[1]);
      s[2] += v2; q[2] = fmaf(v2, v2, q[2]);
      s[3] += v3; q[3] = fmaf(v3, v3, q[3]);
    }
#pragma unroll
    for (int reg = 0; reg < 4; ++reg) {
      float ss = s[reg], qq = q[reg];
#pragma unroll
      for (int m = 1; m < 16; m <<= 1) {
        ss += __shfl_xor(ss, m);
        qq += __shfl_xor(qq, m);
      }
      s_acc[i][reg] = ss;
      q_acc[i][reg] = qq;
    }
  }
  __syncthreads();
  float* red = (float*)Als;
#pragma unroll
  for (int i = 0; i < 4; ++i)
#pragma unroll
    for (int reg = 0; reg < 4; ++reg)
      if (col == 0) {
        int ch = wr * 64 + i * 16 + quad * 4 + reg;
        red[wc * 256 + ch] = s_acc[i][reg];
        red[wc * 256 + 128 + ch] = q_acc[i][reg];
      }
  __syncthreads();
  {
    const int wcb = tid >> 7, ch = tid & 127;
    const int part = (blockIdx.z * 64 + blockIdx.x) * 2 + wcb;
    Psum[part * 256 + oBase + ch] = red[wcb * 256 + ch];
    Psq[part * 256 + oBase + ch]  = red[wcb * 256 + 128 + ch];
  }
}

// ===========================================================================
__global__ __launch_bounds__(1024) void finalize_bn_kernel(
    const float* __restrict__ Psum, const float* __restrict__ Psq,
    const float* __restrict__ gamma, const float* __restrict__ beta,
    float* __restrict__ scale, float* __restrict__ shift) {
  __shared__ float ls[4][2][256];
  const int tid = threadIdx.x;
  const int g = tid >> 8, ch = tid & 255;
  float s = 0.f, q = 0.f;
#pragma unroll 4
  for (int p = g * 128; p < (g + 1) * 128; ++p) {
    s += Psum[p * 256 + ch];
    q += Psq[p * 256 + ch];
  }
  ls[g][0][ch] = s;
  ls[g][1][ch] = q;
  __syncthreads();
  if (tid < 256) {
    float ss = ls[0][0][ch] + ls[1][0][ch] + ls[2][0][ch] + ls[3][0][ch];
    float qq = ls[0][1][ch] + ls[1][1][ch] + ls[2][1][ch] + ls[3][1][ch];
    const float inv_n = 1.f / 32768.f;
    float mean = ss * inv_n;
    float var = qq * inv_n - mean * mean;
    float sc = gamma[ch] * rsqrtf(var + 1e-5f);
    scale[ch] = sc;
    shift[ch] = fmaf(-mean, sc, beta[ch]);
  }
}

__global__ __launch_bounds__(256) void bn_apply_kernel(float* __restrict__ io,
                                                       const float* __restrict__ scale,
                                                       const float* __restrict__ shift) {
  int id = blockIdx.x * 256 + threadIdx.x;
  int row = id >> 11;
  int o = row & 255;
  float sc = scale[o], sh = shift[o];
  float4 v = ((float4*)io)[id];
  v.x = fmaxf(fmaf(v.x, sc, sh), 0.f);
  v.y = fmaxf(fmaf(v.y, sc, sh), 0.f);
  v.z = fmaxf(fmaf(v.z, sc, sh), 0.f);
  v.w = fmaxf(fmaf(v.w, sc, sh), 0.f);
  ((float4*)io)[id] = v;
}

// ===========================================================================
extern "C" void kernel_launch(void* const* d_in, const int* in_sizes, int n_in,
                              void* d_out, int out_size, void* d_ws, size_t ws_size,
                              hipStream_t stream) {
  const float* xyz1 = (const float*)d_in[0];
  const float* xyz2 = (const float*)d_in[1];
  const float* p1   = (const float*)d_in[2];
  const float* p2   = (const float*)d_in[3];
  const float* W1   = (const float*)d_in[4];
  const float* b1   = (const float*)d_in[5];
  const float* g1   = (const float*)d_in[6];
  const float* be1  = (const float*)d_in[7];
  const float* W2   = (const float*)d_in[8];
  const float* b2   = (const float*)d_in[9];
  const float* g2   = (const float*)d_in[10];
  const float* be2  = (const float*)d_in[11];
  float* out = (float*)d_out;

  unsigned short* ws = (unsigned short*)d_ws;
  unsigned short* Xt  = ws;                    // [B][N][384]  12,582,912 bf16
  unsigned short* Y1t = Xt + 12582912;         // [B][N][256]   8,388,608 bf16
  unsigned short* p2t = Y1t + 8388608;         // [B][S][256]   2,097,152 bf16
  unsigned short* W1b = p2t + 2097152;         //      98,304 bf16
  unsigned short* W2b = W1b + 98304;           //      65,536 bf16
  float* Psum1 = (float*)(W2b + 65536);        //     131,072 f
  float* Psq1  = Psum1 + 131072;
  float* Psum2 = Psq1 + 131072;
  float* Psq2  = Psum2 + 131072;
  float* scale1 = Psq2 + 131072;
  float* shift1 = scale1 + 256;
  float* scale2 = shift1 + 256;
  float* shift2 = scale2 + 256;

  prep_kernel<<<2176, 256, 0, stream>>>(W1, W2, W1b, W2b, p1, p2, Xt, p2t);
  knn_interp_kernel<<<512, 512, 0, stream>>>(xyz1, xyz2, p2t, Xt);

  dim3 gg(64, 2, 4);
  gemm_mfma_kernel<CIN_, false><<<gg, 256, 0, stream>>>(
      W1b, Xt, b1, nullptr, nullptr, nullptr, Y1t, Psum1, Psq1);
  finalize_bn_kernel<<<1, 1024, 0, stream>>>(Psum1, Psq1, g1, be1, scale1, shift1);
  gemm_mfma_kernel<H_, true><<<gg, 256, 0, stream>>>(
      W2b, Y1t, b2, scale1, shift1, out, nullptr, Psum2, Psq2);
  finalize_bn_kernel<<<1, 1024, 0, stream>>>(Psum2, Psq2, g2, be2, scale2, shift2);
  bn_apply_kernel<<<8192, 256, 0, stream>>>(out, scale2, shift2);
}